// Round 2
// baseline (227.419 us; speedup 1.0000x reference)
//
#include <hip/hip_runtime.h>

// Conv2d 32x128x56x56 -> 32x256x56x56, 3x3, pad 1, stride 1. fp32 I/O.
// Implicit GEMM, bf16 mfma_f32_16x16x32. K reordered as (ci_hi, kh*kw, ci_lo):
//  - X pre-transformed to NHWC bf16: B-fragment = 8 consecutive ci = 16B.
//  - W2[step][co][ci_lo] (step = ci_hi*9+khw): A-fragments global->reg, L2-hot.
//  - Per ci_hi: x tile (4 rows x 58 cols x 32 ci, halo zeroed) staged in LDS;
//    9 khw positions read b-frags at immediate offsets, no barriers inside.
// ROUND 2 change (occupancy): kernel was latency-bound at 2 waves/SIMD
// (236 unified regs: 112 AGPR acc + 124 VGPR; MfmaUtil 29%, VALU 11%,
// LDS 22%, HBM 20% -> nothing saturated). Shrink wave tile 4m x 7n -> 4m x 4n:
//  - acc 112 -> 64 AGPR, block tile 256co x 64p, grid 896 -> 1568.
//  - launch_bounds(256,3): 3 blocks/CU = 3 waves/SIMD (+50% latency hiding).
//  - m=4 kept, so B-fragment LDS traffic per FLOP is unchanged.
//  - A-fragments manually pipelined one khw step ahead (an[]).
//  - prep_x + prep_w merged into one launch.
// 64p tiles are not row-aligned: tile rows r0..r0+1 (64*pb%56 <= 48 => never
// spans 3 output rows), staging rows r0-1..r0+2 -- same 4x58 tile as before.

#define CIN   128
#define COUT  256
#define HWID  56
#define IMG   (HWID*HWID)     // 3136
#define NIMG  32
#define CSTR  40              // Bs ci stride (shorts), 80B: 16B-aligned
#define BROW  (58*CSTR)       // Bs row stride (shorts)
#define NXB   (NIMG*4*49)     // prep_x blocks = 6272

typedef __attribute__((ext_vector_type(8))) short short8;   // 8 bf16 = 4 VGPRs
typedef __attribute__((ext_vector_type(4))) float float4v;  // MFMA acc

__device__ __forceinline__ unsigned short f2bf(float f) {
    unsigned int u = __builtin_bit_cast(unsigned int, f);
    u += 0x7FFFu + ((u >> 16) & 1u);   // RNE
    return (unsigned short)(u >> 16);
}

// Merged prep: blocks [0, NXB) transform X (NCHW fp32 -> NHWC bf16, LDS
// transpose, float4 reads / short8 writes); blocks [NXB, NXB+1152) build
// W2[((ci_hi*9+kh*3+kw)*256+co)*32+ci_lo] = bf16(w[co][ci_hi*32+ci_lo][kh][kw]).
__global__ __launch_bounds__(256) void prep_kernel(const float* __restrict__ x,
                                                   const float* __restrict__ w,
                                                   unsigned short* __restrict__ X2,
                                                   unsigned short* __restrict__ W2) {
    __shared__ unsigned short Ls[32 * 66];   // 4224 B (x-path only)

    if (blockIdx.x >= NXB) {                 // ---- W path ----
        int o = (blockIdx.x - NXB) * 256 + threadIdx.x;   // 294912 total
        int ci_lo = o & 31;
        int co    = (o >> 5) & 255;
        int s     = o >> 13;                 // 0..35
        int ci_hi = s / 9;
        int r9    = s - ci_hi * 9;           // kh*3+kw
        W2[o] = f2bf(w[(co * CIN + ci_hi * 32 + ci_lo) * 9 + r9]);
        return;
    }

    // ---- X path: tile 32 ci x 64 p ----
    int b  = blockIdx.x;               // n*(4*49) + cb*49 + pb
    int pb = b % 49;
    int t  = b / 49;
    int cb = t & 3;
    int n  = t >> 2;
    int p0 = pb * 64, ci0 = cb * 32;

    const float* src = x + ((long)n * CIN + ci0) * IMG + p0;
    #pragma unroll
    for (int it = 0; it < 2; ++it) {
        int flat = it * 256 + threadIdx.x;   // 0..511
        int ci_l = flat >> 4;                // 0..31
        int c4   = flat & 15;                // float4 within 64 p
        float4 v = *(const float4*)(src + ci_l * IMG + c4 * 4);   // coalesced 16B
        unsigned int lo = (unsigned int)f2bf(v.x) | ((unsigned int)f2bf(v.y) << 16);
        unsigned int hi = (unsigned int)f2bf(v.z) | ((unsigned int)f2bf(v.w) << 16);
        *(unsigned int*)(&Ls[ci_l * 66 + c4 * 4])     = lo;
        *(unsigned int*)(&Ls[ci_l * 66 + c4 * 4 + 2]) = hi;
    }
    __syncthreads();
    int p_l = threadIdx.x >> 2;   // 0..63
    int c8  = threadIdx.x & 3;    // 8-ci chunk
    unsigned short* dst = X2 + ((long)n * IMG + p0) * CIN + ci0;
    short8 o;
    #pragma unroll
    for (int j = 0; j < 8; ++j)
        o[j] = (short)Ls[(c8 * 8 + j) * 66 + p_l];
    *(short8*)(&dst[(long)p_l * CIN + c8 * 8]) = o;   // coalesced 16B
}

// Issue global loads for x tile CIHI into rx[] (rows r0-1 .. r0+2).
#define ISSUE_TILE(CIHI) do {                                                   \
    _Pragma("unroll")                                                           \
    for (int it = 0; it < 4; ++it) {                                            \
        int idx = it * 256 + tid;      /* 0..1023, valid < 928 */               \
        int ci8 = idx & 3;                                                      \
        int rc  = idx >> 2;            /* r*58 + c, valid < 232 */              \
        uint4 v = make_uint4(0u, 0u, 0u, 0u);                                   \
        if (rc < 232) {                                                         \
            int r = rc / 58;                                                    \
            int c = rc - r * 58;                                                \
            int h = r0 - 1 + r;                                                 \
            int w = c - 1;                                                      \
            if ((unsigned)h < 56u && (unsigned)w < 56u)                         \
                v = *(const uint4*)(xnb + ((h * HWID + w) * CIN + (CIHI) * 32 + ci8 * 8)); \
        }                                                                       \
        rx[it] = v;                                                             \
    }                                                                           \
} while (0)

__global__ __launch_bounds__(256, 3)
void conv_mfma_kernel(const unsigned short* __restrict__ X2,
                      const unsigned short* __restrict__ W2,
                      float* __restrict__ out) {
    __shared__ __align__(16) unsigned short Bs[4 * BROW];   // 18560 B

    const int tid  = threadIdx.x;
    const int lane = tid & 63;
    const int wv   = tid >> 6;
    const int l15  = lane & 15;
    const int quad = lane >> 4;

    const int pt    = blockIdx.x;      // 0..1567
    const int n_img = pt / 49;
    const int pb    = pt - n_img * 49;
    const int p0    = pb * 64;         // 64 output positions per block
    const int r0    = p0 / HWID;       // first output row in tile
    const int off56 = p0 - r0 * HWID;  // 0..48, multiple of 8

    // per-lane b-frag bases (short index into Bs), one per n-tile
    int boff[4];
    #pragma unroll
    for (int n = 0; n < 4; ++n) {
        int pl   = off56 + n * 16 + l15;        // 0..111
        int prow = (pl >= 56) ? 1 : 0;
        int pcol = pl - prow * 56;
        boff[n]  = (prow * 58 + pcol) * CSTR + quad * 8;
    }

    // a-frag base: W2[step][co][ci_lo], co = wv*64 + m*16 + l15, ci_lo = quad*8+j
    const unsigned short* wbase = W2 + (wv * 64 + l15) * 32 + quad * 8;

    float4v acc[4][4];
    #pragma unroll
    for (int m = 0; m < 4; ++m)
        #pragma unroll
        for (int n = 0; n < 4; ++n)
            acc[m][n] = (float4v){0.f, 0.f, 0.f, 0.f};

    const unsigned short* xnb = X2 + (long)n_img * (IMG * CIN);

    uint4 rx[4];
    ISSUE_TILE(0);                      // prologue: tile 0 loads in flight

    // A-fragment pipeline: a[] holds current step, an[] next step.
    short8 a[4], an[4];
    #pragma unroll
    for (int m = 0; m < 4; ++m)
        a[m] = *(const short8*)(wbase + 0 * 8192 + m * 512);

    for (int ci_hi = 0; ci_hi < 4; ++ci_hi) {
        __syncthreads();   // protect Bs from previous iteration's readers

        // ---- drain rx (vmcnt) and write staged tile to LDS ----
        #pragma unroll
        for (int it = 0; it < 4; ++it) {
            int idx = it * 256 + tid;
            int rc  = idx >> 2;
            if (rc < 232) {
                int ci8 = idx & 3;
                *(uint4*)(&Bs[rc * CSTR + ci8 * 8]) = rx[it];
            }
        }
        __syncthreads();

        // ---- prefetch next x tile: loads fly under the 9-step compute ----
        if (ci_hi < 3) ISSUE_TILE(ci_hi + 1);

        // ---- 9 khw positions, NO barriers (Bs read-only here) ----
        #pragma unroll
        for (int khw = 0; khw < 9; ++khw) {
            const int kh = khw / 3, kw = khw - (khw / 3) * 3;
            const int step = ci_hi * 9 + khw;
            // issue next step's a-frags first (covers L2 latency with MFMAs)
            if (step < 35) {
                #pragma unroll
                for (int m = 0; m < 4; ++m)
                    an[m] = *(const short8*)(wbase + (step + 1) * 8192 + m * 512);
            }
            short8 bfr[4];
            #pragma unroll
            for (int n = 0; n < 4; ++n)
                bfr[n] = *(const short8*)(&Bs[boff[n] + (kh * 58 + kw) * CSTR]);
            #pragma unroll
            for (int m = 0; m < 4; ++m)
                #pragma unroll
                for (int n = 0; n < 4; ++n)
                    acc[m][n] = __builtin_amdgcn_mfma_f32_16x16x32_bf16(a[m], bfr[n], acc[m][n], 0, 0, 0);
            if (step < 35) {
                #pragma unroll
                for (int m = 0; m < 4; ++m)
                    a[m] = an[m];
            }
        }
    }

    // ---- epilogue: C/D layout col(p)=lane&15, row(co)=quad*4+reg ----
    float* obase = out + (long)n_img * (COUT * IMG) + p0;
    #pragma unroll
    for (int m = 0; m < 4; ++m) {
        #pragma unroll
        for (int r = 0; r < 4; ++r) {
            int co = wv * 64 + m * 16 + quad * 4 + r;
            float* orow = obase + (long)co * IMG;
            #pragma unroll
            for (int n = 0; n < 4; ++n)
                orow[n * 16 + l15] = acc[m][n][r];
        }
    }
}

extern "C" void kernel_launch(void* const* d_in, const int* in_sizes, int n_in,
                              void* d_out, int out_size, void* d_ws, size_t ws_size,
                              hipStream_t stream) {
    const float* x  = (const float*)d_in[0];
    const float* wt = (const float*)d_in[1];
    float* out = (float*)d_out;

    unsigned short* X2 = (unsigned short*)d_ws;            // 12,845,056 shorts (NHWC bf16)
    unsigned short* W2 = X2 + (long)NIMG * CIN * IMG;      // 294,912 shorts

    prep_kernel<<<NXB + (COUT * CIN * 9) / 256, 256, 0, stream>>>(x, wt, X2, W2);
    conv_mfma_kernel<<<NIMG * 49, 256, 0, stream>>>(X2, W2, out);
}

// Round 3
// 187.512 us; speedup vs baseline: 1.2128x; 1.2128x over previous
//
#include <hip/hip_runtime.h>

// Conv2d 32x128x56x56 -> 32x256x56x56, 3x3, pad 1, stride 1. fp32 I/O.
// Implicit GEMM, bf16 mfma_f32_16x16x32.
//  - X pre-transformed to NHWC bf16 (prep), W2[step][co][ci_lo] step-major.
//  - ROUND 3: single full-ci staging. The whole 4-row x 58-col x 128-ci x
//    tile (63.1 KB LDS, padded rows of 136 shorts = 272B) is staged ONCE,
//    then ONE barrier, then 36 steps (4 ci_hi x 9 khw) of pure
//    {A global->reg, B ds_read_b128, 28 MFMA} with NO barriers. R0/R1 had
//    8 barriers/block (re-staging the same pixels 4x for ci slices); the
//    barrier+vmcnt-drain convoys cost ~50 us vs the 28.5 us MFMA floor
//    (3528 MFMA/SIMD x 19.4 cy). R2's smaller p-tile doubled FETCH ->
//    reverted to 112p/896-block grid.
// Block: 256 thr = 4 waves, tile 256co x 112p (2 output rows). Wave: 4m x 7n.
// Xs rows 272B: ds_read_b128 16-lane groups spread uniformly over the 8
// 16B bank-slots (2 lanes/slot = free). Reg-staged writes (pad rules out
// global_load_lds).

#define CIN   128
#define COUT  256
#define HWID  56
#define IMG   (HWID*HWID)     // 3136
#define NIMG  32
#define RSTR  136             // Xs pixel stride in shorts (272B, 16B-aligned)
#define NXB   (NIMG*4*49)     // prep x-blocks = 6272

typedef __attribute__((ext_vector_type(8))) short short8;   // 8 bf16 = 4 VGPRs
typedef __attribute__((ext_vector_type(4))) float float4v;  // MFMA acc

__device__ __forceinline__ unsigned short f2bf(float f) {
    unsigned int u = __builtin_bit_cast(unsigned int, f);
    u += 0x7FFFu + ((u >> 16) & 1u);   // RNE
    return (unsigned short)(u >> 16);
}

// Merged prep: blocks [0, NXB) transform X (NCHW fp32 -> NHWC bf16, LDS
// transpose, float4 reads / short8 writes); blocks [NXB, NXB+1152) build
// W2[((ci_hi*9+kh*3+kw)*256+co)*32+ci_lo] = bf16(w[co][ci_hi*32+ci_lo][kh][kw]).
__global__ __launch_bounds__(256) void prep_kernel(const float* __restrict__ x,
                                                   const float* __restrict__ w,
                                                   unsigned short* __restrict__ X2,
                                                   unsigned short* __restrict__ W2) {
    __shared__ unsigned short Ls[32 * 66];   // 4224 B (x-path only)

    if (blockIdx.x >= NXB) {                 // ---- W path ----
        int o = (blockIdx.x - NXB) * 256 + threadIdx.x;   // 294912 total
        int ci_lo = o & 31;
        int co    = (o >> 5) & 255;
        int s     = o >> 13;                 // 0..35
        int ci_hi = s / 9;
        int r9    = s - ci_hi * 9;           // kh*3+kw
        W2[o] = f2bf(w[(co * CIN + ci_hi * 32 + ci_lo) * 9 + r9]);
        return;
    }

    // ---- X path: tile 32 ci x 64 p ----
    int b  = blockIdx.x;               // n*(4*49) + cb*49 + pb
    int pb = b % 49;
    int t  = b / 49;
    int cb = t & 3;
    int n  = t >> 2;
    int p0 = pb * 64, ci0 = cb * 32;

    const float* src = x + ((long)n * CIN + ci0) * IMG + p0;
    #pragma unroll
    for (int it = 0; it < 2; ++it) {
        int flat = it * 256 + threadIdx.x;   // 0..511
        int ci_l = flat >> 4;                // 0..31
        int c4   = flat & 15;                // float4 within 64 p
        float4 v = *(const float4*)(src + ci_l * IMG + c4 * 4);   // coalesced 16B
        unsigned int lo = (unsigned int)f2bf(v.x) | ((unsigned int)f2bf(v.y) << 16);
        unsigned int hi = (unsigned int)f2bf(v.z) | ((unsigned int)f2bf(v.w) << 16);
        *(unsigned int*)(&Ls[ci_l * 66 + c4 * 4])     = lo;
        *(unsigned int*)(&Ls[ci_l * 66 + c4 * 4 + 2]) = hi;
    }
    __syncthreads();
    int p_l = threadIdx.x >> 2;   // 0..63
    int c8  = threadIdx.x & 3;    // 8-ci chunk
    unsigned short* dst = X2 + ((long)n * IMG + p0) * CIN + ci0;
    short8 o;
    #pragma unroll
    for (int j = 0; j < 8; ++j)
        o[j] = (short)Ls[(c8 * 8 + j) * 66 + p_l];
    *(short8*)(&dst[(long)p_l * CIN + c8 * 8]) = o;   // coalesced 16B
}

// Stage a batch of 16B chunks of the x tile: issue all loads, then write.
// idx = (IT0+it)*256 + tid; chunk = (rc, ci16): rc = r*58+c in [0,232),
// ci16 = 16-byte chunk of the 128-ci row.
#define STAGE_BATCH(IT0, CNT) do {                                              \
    _Pragma("unroll")                                                           \
    for (int it = 0; it < (CNT); ++it) {                                        \
        int idx  = ((IT0) + it) * 256 + tid;                                    \
        int ci16 = idx & 15;                                                    \
        int rc   = idx >> 4;                                                    \
        uint4 v = make_uint4(0u, 0u, 0u, 0u);                                   \
        if (rc < 232) {                                                         \
            int r = rc / 58;                                                    \
            int c = rc - r * 58;                                                \
            int h = h0 - 1 + r;                                                 \
            int w = c - 1;                                                      \
            if ((unsigned)h < 56u && (unsigned)w < 56u)                         \
                v = *(const uint4*)(xnb + ((h * HWID + w) * CIN + ci16 * 8));   \
        }                                                                       \
        stbuf[it] = v;                                                          \
    }                                                                           \
    _Pragma("unroll")                                                           \
    for (int it = 0; it < (CNT); ++it) {                                        \
        int idx  = ((IT0) + it) * 256 + tid;                                    \
        int ci16 = idx & 15;                                                    \
        int rc   = idx >> 4;                                                    \
        if (rc < 232)                                                           \
            *(uint4*)(&Xs[rc * RSTR + ci16 * 8]) = stbuf[it];                   \
    }                                                                           \
} while (0)

__global__ __launch_bounds__(256, 2)
void conv_mfma_kernel(const unsigned short* __restrict__ X2,
                      const unsigned short* __restrict__ W2,
                      float* __restrict__ out) {
    __shared__ __align__(16) unsigned short Xs[232 * RSTR];   // 63104 B

    const int tid  = threadIdx.x;
    const int lane = tid & 63;
    const int wv   = tid >> 6;
    const int l15  = lane & 15;
    const int quad = lane >> 4;

    const int pt    = blockIdx.x;      // 0..895
    const int n_img = pt / 28;
    const int h0    = (pt % 28) * 2;   // output rows h0, h0+1

    // per-lane b-frag bases (short index into Xs), one per n-tile
    int boff[7];
    #pragma unroll
    for (int n = 0; n < 7; ++n) {
        int p    = n * 16 + l15;
        int prow = (p >= 56) ? 1 : 0;
        int pcol = p - prow * 56;
        boff[n]  = (prow * 58 + pcol) * RSTR + quad * 8;
    }

    // a-frag base: W2[step][co][ci_lo], co = wv*64 + m*16 + l15, ci_lo = quad*8+j
    const unsigned short* wbase = W2 + (wv * 64 + l15) * 32 + quad * 8;

    const unsigned short* xnb = X2 + (long)n_img * (IMG * CIN);

    // ---- stage the full 4 rows x 58 cols x 128 ci tile, ONE barrier ----
    {
        uint4 stbuf[8];
        STAGE_BATCH(0, 8);     // chunks 0..2047
        STAGE_BATCH(8, 7);     // chunks 2048..3711 (last round partial)
    }
    __syncthreads();

    float4v acc[4][7];
    #pragma unroll
    for (int m = 0; m < 4; ++m)
        #pragma unroll
        for (int n = 0; n < 7; ++n)
            acc[m][n] = (float4v){0.f, 0.f, 0.f, 0.f};

    // A-fragment pipeline: a[] current step, an[] next step.
    short8 a[4], an[4];
    #pragma unroll
    for (int m = 0; m < 4; ++m)
        a[m] = *(const short8*)(wbase + m * 512);

    // ---- 36 steps, NO barriers ----
    #pragma unroll
    for (int ci_hi = 0; ci_hi < 4; ++ci_hi) {
        #pragma unroll
        for (int khw = 0; khw < 9; ++khw) {
            const int step = ci_hi * 9 + khw;
            const int kh = khw / 3, kw = khw - (khw / 3) * 3;
            if (step < 35) {
                #pragma unroll
                for (int m = 0; m < 4; ++m)
                    an[m] = *(const short8*)(wbase + (step + 1) * 8192 + m * 512);
            }
            short8 bfr[7];
            #pragma unroll
            for (int n = 0; n < 7; ++n)
                bfr[n] = *(const short8*)(&Xs[boff[n] + (kh * 58 + kw) * RSTR + ci_hi * 32]);
            #pragma unroll
            for (int m = 0; m < 4; ++m)
                #pragma unroll
                for (int n = 0; n < 7; ++n)
                    acc[m][n] = __builtin_amdgcn_mfma_f32_16x16x32_bf16(a[m], bfr[n], acc[m][n], 0, 0, 0);
            if (step < 35) {
                #pragma unroll
                for (int m = 0; m < 4; ++m)
                    a[m] = an[m];
            }
        }
    }

    // ---- epilogue: C/D layout col(p)=lane&15, row(co)=quad*4+reg ----
    float* obase = out + (long)n_img * (COUT * IMG) + h0 * HWID;
    #pragma unroll
    for (int m = 0; m < 4; ++m) {
        #pragma unroll
        for (int r = 0; r < 4; ++r) {
            int co = wv * 64 + m * 16 + quad * 4 + r;
            float* orow = obase + (long)co * IMG;
            #pragma unroll
            for (int n = 0; n < 7; ++n)
                orow[n * 16 + l15] = acc[m][n][r];
        }
    }
}

extern "C" void kernel_launch(void* const* d_in, const int* in_sizes, int n_in,
                              void* d_out, int out_size, void* d_ws, size_t ws_size,
                              hipStream_t stream) {
    const float* x  = (const float*)d_in[0];
    const float* wt = (const float*)d_in[1];
    float* out = (float*)d_out;

    unsigned short* X2 = (unsigned short*)d_ws;            // 12,845,056 shorts (NHWC bf16)
    unsigned short* W2 = X2 + (long)NIMG * CIN * IMG;      // 294,912 shorts

    prep_kernel<<<NXB + (COUT * CIN * 9) / 256, 256, 0, stream>>>(x, wt, X2, W2);
    conv_mfma_kernel<<<NIMG * 28, 256, 0, stream>>>(X2, W2, out);
}